// Round 1
// baseline (1196.676 us; speedup 1.0000x reference)
//
#include <hip/hip_runtime.h>
#include <hip/hip_bf16.h>
#include <math.h>

#define N_NODES 30000
#define N_EDGES 480000
#define EE_TOT  510000   // edges + self loops
#define F_INK   1280
#define HC      512      // HEADS * C (4 * 128)
#define C_PH    128
#define NHID    64

// ---------- wave helpers (wave64) ----------
__device__ inline float wred_max(float v){
  #pragma unroll
  for (int o = 32; o; o >>= 1) v = fmaxf(v, __shfl_xor(v, o));
  return v;
}
__device__ inline float wred_sum(float v){
  #pragma unroll
  for (int o = 32; o; o >>= 1) v += __shfl_xor(v, o);
  return v;
}

// ---------- GEMM1: h = x @ W_gat  [30000,1280]@[1280,512] ----------
__global__ __launch_bounds__(256) void gemm1_f32(const float* __restrict__ A,
                                                 const float* __restrict__ B,
                                                 float* __restrict__ C){
  __shared__ float As[16][68];   // [k][m] transposed, padded
  __shared__ float Bs[16][68];   // [k][n], padded
  const int t  = threadIdx.x;
  const int tx = t & 15, ty = t >> 4;
  const int bn = blockIdx.x * 64;
  const int bm = blockIdx.y * 64;
  const int am = t >> 2, ak = (t & 3) * 4;       // A-load: row am, 4 k's
  const int bk = t >> 4, bn4 = (t & 15) * 4;     // B-load: k bk, 4 n's
  int arow = bm + am; if (arow >= N_NODES) arow = N_NODES - 1;  // clamp loads
  const float* Aptr = A + (size_t)arow * F_INK + ak;
  const float* Bptr = B + (size_t)bk * HC + bn + bn4;
  float acc[4][4] = {};
  for (int k0 = 0; k0 < F_INK; k0 += 16){
    float4 va = *(const float4*)(Aptr + k0);
    float4 vb = *(const float4*)(Bptr + (size_t)k0 * HC);
    __syncthreads();
    As[ak+0][am] = va.x; As[ak+1][am] = va.y; As[ak+2][am] = va.z; As[ak+3][am] = va.w;
    *(float4*)&Bs[bk][bn4] = vb;
    __syncthreads();
    #pragma unroll
    for (int kk = 0; kk < 16; kk++){
      float4 a4 = *(const float4*)&As[kk][ty*4];
      float4 b4 = *(const float4*)&Bs[kk][tx*4];
      acc[0][0] += a4.x*b4.x; acc[0][1] += a4.x*b4.y; acc[0][2] += a4.x*b4.z; acc[0][3] += a4.x*b4.w;
      acc[1][0] += a4.y*b4.x; acc[1][1] += a4.y*b4.y; acc[1][2] += a4.y*b4.z; acc[1][3] += a4.y*b4.w;
      acc[2][0] += a4.z*b4.x; acc[2][1] += a4.z*b4.y; acc[2][2] += a4.z*b4.z; acc[2][3] += a4.z*b4.w;
      acc[3][0] += a4.w*b4.x; acc[3][1] += a4.w*b4.y; acc[3][2] += a4.w*b4.z; acc[3][3] += a4.w*b4.w;
    }
  }
  #pragma unroll
  for (int i = 0; i < 4; i++){
    int row = bm + ty*4 + i;
    if (row < N_NODES){
      float4 v; v.x = acc[i][0]; v.y = acc[i][1]; v.z = acc[i][2]; v.w = acc[i][3];
      *(float4*)&C[(size_t)row * HC + bn + tx*4] = v;
    }
  }
}

// ---------- per-node attention dots: a_src/a_dst [N,4] ----------
__global__ __launch_bounds__(256) void attdot(const float* __restrict__ h,
    const float* __restrict__ att_s, const float* __restrict__ att_d,
    float* __restrict__ a_src, float* __restrict__ a_dst){
  int n = blockIdx.x;
  int w = threadIdx.x >> 6;      // head
  int lane = threadIdx.x & 63;
  const float* hr = h + (size_t)n * HC + w * C_PH;
  float h0 = hr[lane], h1 = hr[lane + 64];
  const float* as = att_s + w * C_PH;
  const float* ad = att_d + w * C_PH;
  float s1 = h0 * as[lane] + h1 * as[lane + 64];
  float s2 = h0 * ad[lane] + h1 * ad[lane + 64];
  s1 = wred_sum(s1); s2 = wred_sum(s2);
  if (lane == 0){ a_src[n*4 + w] = s1; a_dst[n*4 + w] = s2; }
}

// ---------- CSR build ----------
__global__ void count_k(const int* __restrict__ ei, int* __restrict__ counts){
  int e = blockIdx.x * 256 + threadIdx.x;
  if (e >= EE_TOT) return;
  int d = (e < N_EDGES) ? ei[N_EDGES + e] : (e - N_EDGES);
  atomicAdd(&counts[d], 1);
}

__global__ __launch_bounds__(1024) void scan_k(const int* __restrict__ counts,
                                               int* __restrict__ offsets){
  __shared__ int sh[1024];
  int t = threadIdx.x;
  int base = t * 30;
  int tot = 0;
  for (int i = 0; i < 30; i++){
    int idx = base + i;
    tot += (idx < N_NODES) ? counts[idx] : 0;
  }
  sh[t] = tot; __syncthreads();
  for (int o = 1; o < 1024; o <<= 1){
    int v = (t >= o) ? sh[t - o] : 0;
    __syncthreads();
    sh[t] += v;
    __syncthreads();
  }
  int run = sh[t] - tot;  // exclusive prefix
  for (int i = 0; i < 30; i++){
    int idx = base + i;
    if (idx < N_NODES){ offsets[idx] = run; run += counts[idx]; }
  }
  if (t == 1023) offsets[N_NODES] = sh[1023];
}

__global__ void fill_k(const int* __restrict__ ei, const float* __restrict__ ew,
                       int* __restrict__ cursor, const int* __restrict__ offsets,
                       int* __restrict__ src_s, float* __restrict__ w_s){
  int e = blockIdx.x * 256 + threadIdx.x;
  if (e >= EE_TOT) return;
  int s, d; float w;
  if (e < N_EDGES){ s = ei[e]; d = ei[N_EDGES + e]; w = ew[e]; }
  else            { s = d = e - N_EDGES; w = 1.0f; }
  int pos = offsets[d] + atomicAdd(&cursor[d], 1);
  src_s[pos] = s; w_s[pos] = w;
}

// ---------- segment softmax (per dst node) + GCN degree ----------
__global__ __launch_bounds__(64) void attnprep(const int* __restrict__ offsets,
    const int* __restrict__ src_s, const float* __restrict__ w_s,
    const float* __restrict__ a_src, const float* __restrict__ a_dst,
    float* __restrict__ alpha, float* __restrict__ dinv){
  int n = blockIdx.x, lane = threadIdx.x;
  int off = offsets[n], end = offsets[n + 1];
  float4 ad = *(const float4*)&a_dst[n * 4];
  float m0 = -1e30f, m1 = -1e30f, m2 = -1e30f, m3 = -1e30f;
  for (int i = off + lane; i < end; i += 64){
    int s = src_s[i];
    float4 as = *(const float4*)&a_src[s * 4];
    float l0 = as.x + ad.x; l0 = (l0 > 0.f) ? l0 : 0.2f * l0;
    float l1 = as.y + ad.y; l1 = (l1 > 0.f) ? l1 : 0.2f * l1;
    float l2 = as.z + ad.z; l2 = (l2 > 0.f) ? l2 : 0.2f * l2;
    float l3 = as.w + ad.w; l3 = (l3 > 0.f) ? l3 : 0.2f * l3;
    m0 = fmaxf(m0, l0); m1 = fmaxf(m1, l1); m2 = fmaxf(m2, l2); m3 = fmaxf(m3, l3);
  }
  m0 = wred_max(m0); m1 = wred_max(m1); m2 = wred_max(m2); m3 = wred_max(m3);
  float s0 = 0, s1 = 0, s2 = 0, s3 = 0, wsum = 0;
  for (int i = off + lane; i < end; i += 64){
    int s = src_s[i];
    float4 as = *(const float4*)&a_src[s * 4];
    float l0 = as.x + ad.x; l0 = (l0 > 0.f) ? l0 : 0.2f * l0;
    float l1 = as.y + ad.y; l1 = (l1 > 0.f) ? l1 : 0.2f * l1;
    float l2 = as.z + ad.z; l2 = (l2 > 0.f) ? l2 : 0.2f * l2;
    float l3 = as.w + ad.w; l3 = (l3 > 0.f) ? l3 : 0.2f * l3;
    float e0 = expf(l0 - m0), e1 = expf(l1 - m1), e2 = expf(l2 - m2), e3 = expf(l3 - m3);
    float4 av; av.x = e0; av.y = e1; av.z = e2; av.w = e3;
    *(float4*)&alpha[(size_t)i * 4] = av;
    s0 += e0; s1 += e1; s2 += e2; s3 += e3;
    wsum += w_s[i];
  }
  s0 = wred_sum(s0); s1 = wred_sum(s1); s2 = wred_sum(s2); s3 = wred_sum(s3);
  wsum = wred_sum(wsum);
  if (lane == 0) dinv[n] = (wsum > 0.f) ? rsqrtf(wsum) : 0.f;
  float r0 = 1.f / (s0 + 1e-16f), r1 = 1.f / (s1 + 1e-16f);
  float r2 = 1.f / (s2 + 1e-16f), r3 = 1.f / (s3 + 1e-16f);
  for (int i = off + lane; i < end; i += 64){
    float4 av = *(float4*)&alpha[(size_t)i * 4];
    av.x *= r0; av.y *= r1; av.z *= r2; av.w *= r3;
    *(float4*)&alpha[(size_t)i * 4] = av;
  }
}

// ---------- GAT message aggregation: out1[n] = sum h[src]*alpha ----------
__global__ __launch_bounds__(256) void gatagg(const int* __restrict__ offsets,
    const int* __restrict__ src_s, const float* __restrict__ alpha,
    const float* __restrict__ h, const float* __restrict__ b_gat,
    float* __restrict__ out1){
  __shared__ int    s_l[64];
  __shared__ float4 a_l[64];
  int n = blockIdx.x, t = threadIdx.x;
  int off = offsets[n], deg = offsets[n + 1] - off;
  float acc1 = 0, acc2 = 0;
  for (int done = 0; done < deg; done += 64){
    int ce = deg - done; if (ce > 64) ce = 64;
    __syncthreads();
    if (t < ce){
      s_l[t] = src_s[off + done + t];
      a_l[t] = *(const float4*)&alpha[(size_t)(off + done + t) * 4];
    }
    __syncthreads();
    for (int i = 0; i < ce; i++){
      const float* hr = h + (size_t)s_l[i] * HC;
      float4 av = a_l[i];
      float a1 = (t < 128) ? av.x : av.y;   // channel t     -> head 0/1
      float a2 = (t < 128) ? av.z : av.w;   // channel t+256 -> head 2/3
      acc1 += hr[t]       * a1;
      acc2 += hr[t + 256] * a2;
    }
  }
  out1[(size_t)n * HC + t]       = acc1 + b_gat[t];
  out1[(size_t)n * HC + t + 256] = acc2 + b_gat[t + 256];
}

// ---------- BatchNorm stats ----------
__global__ __launch_bounds__(256) void bnstats(const float* __restrict__ out1,
                                               float* __restrict__ bnacc){
  int t = threadIdx.x;
  float s1 = 0, q1 = 0, s2 = 0, q2 = 0;
  for (int n = blockIdx.x; n < N_NODES; n += gridDim.x){
    float v1 = out1[(size_t)n * HC + t];
    float v2 = out1[(size_t)n * HC + t + 256];
    s1 += v1; q1 += v1 * v1; s2 += v2; q2 += v2 * v2;
  }
  atomicAdd(&bnacc[t], s1);        atomicAdd(&bnacc[512 + t], q1);
  atomicAdd(&bnacc[t + 256], s2);  atomicAdd(&bnacc[512 + t + 256], q2);
}

__global__ void bnfinal(const float* __restrict__ bnacc, const float* __restrict__ gam,
                        const float* __restrict__ bet, float* __restrict__ bnp){
  int c = blockIdx.x * 256 + threadIdx.x;
  if (c >= 512) return;
  float mean = bnacc[c] * (1.0f / N_NODES);
  float var  = bnacc[512 + c] * (1.0f / N_NODES) - mean * mean;
  float sc = gam[c] * rsqrtf(var + 1e-5f);
  bnp[c] = sc;
  bnp[512 + c] = bet[c] - mean * sc;
}

// ---------- GEMM2 (fused BN+ReLU): h2 = relu(bn(out1)) @ W_gcn ----------
__global__ __launch_bounds__(256) void gemm2(const float* __restrict__ out1,
    const float* __restrict__ bnp, const float* __restrict__ Wg,
    float* __restrict__ h2){
  __shared__ float xr[4][512];
  __shared__ float wt[128][64];
  int t = threadIdx.x;
  int n0 = blockIdx.x * 4;
  for (int r = 0; r < 4; r++){
    int n = n0 + r;
    if (n < N_NODES){
      float v = out1[(size_t)n * HC + t] * bnp[t] + bnp[512 + t];
      xr[r][t] = v > 0.f ? v : 0.f;
      v = out1[(size_t)n * HC + t + 256] * bnp[t + 256] + bnp[512 + t + 256];
      xr[r][t + 256] = v > 0.f ? v : 0.f;
    } else { xr[r][t] = 0.f; xr[r][t + 256] = 0.f; }
  }
  int w = t >> 6, j = t & 63;
  float acc = 0.f;
  for (int k0 = 0; k0 < 512; k0 += 128){
    __syncthreads();
    for (int i = t; i < 128 * 64; i += 256)
      wt[i >> 6][i & 63] = Wg[(size_t)(k0 + (i >> 6)) * 64 + (i & 63)];
    __syncthreads();
    #pragma unroll 8
    for (int k = 0; k < 128; k++) acc += xr[w][k0 + k] * wt[k][j];
  }
  int n = n0 + w;
  if (n < N_NODES) h2[(size_t)n * NHID + j] = acc;
}

// ---------- GCN aggregation ----------
__global__ __launch_bounds__(64) void gcnagg(const int* __restrict__ offsets,
    const int* __restrict__ src_s, const float* __restrict__ w_s,
    const float* __restrict__ dinv, const float* __restrict__ h2,
    const float* __restrict__ b_gcn, float* __restrict__ out){
  int n = blockIdx.x, j = threadIdx.x;
  int off = offsets[n], end = offsets[n + 1];
  float dv = dinv[n];
  float acc = 0.f;
  for (int i = off; i < end; i++){
    int s = src_s[i];
    float nrm = dinv[s] * w_s[i] * dv;
    acc += h2[(size_t)s * NHID + j] * nrm;
  }
  out[(size_t)n * NHID + j] = acc + b_gcn[j];
}

extern "C" void kernel_launch(void* const* d_in, const int* in_sizes, int n_in,
                              void* d_out, int out_size, void* d_ws, size_t ws_size,
                              hipStream_t stream){
  const float* x    = (const float*)d_in[0];
  const int*   ei   = (const int*)d_in[1];
  const float* ew   = (const float*)d_in[2];
  const float* Wgat = (const float*)d_in[3];
  const float* atts = (const float*)d_in[4];
  const float* attd = (const float*)d_in[5];
  const float* bgat = (const float*)d_in[6];
  const float* gam  = (const float*)d_in[7];
  const float* bet  = (const float*)d_in[8];
  const float* Wgcn = (const float*)d_in[9];
  const float* bgcn = (const float*)d_in[10];
  float* out = (float*)d_out;

  char* ws = (char*)d_ws;
  size_t cur = 0;
  auto nb = [&](size_t bytes){ cur = (cur + 255) & ~(size_t)255; size_t r = cur; cur += bytes; return r; };
  int*   counts  = (int*)  (ws + nb((size_t)N_NODES * 4));
  int*   cursor  = (int*)  (ws + nb((size_t)N_NODES * 4));
  float* bnacc   = (float*)(ws + nb(1024 * 4));
  size_t zbytes  = cur;                         // everything above must start at 0
  float* h       = (float*)(ws + nb((size_t)N_NODES * HC * 4));
  float* a_src   = (float*)(ws + nb((size_t)N_NODES * 4 * 4));
  float* a_dst   = (float*)(ws + nb((size_t)N_NODES * 4 * 4));
  int*   offsets = (int*)  (ws + nb((size_t)(N_NODES + 1) * 4));
  int*   src_s   = (int*)  (ws + nb((size_t)EE_TOT * 4));
  float* w_s     = (float*)(ws + nb((size_t)EE_TOT * 4));
  float* alpha   = (float*)(ws + nb((size_t)EE_TOT * 16));
  float* out1    = (float*)(ws + nb((size_t)N_NODES * HC * 4));
  float* bnp     = (float*)(ws + nb(1024 * 4));
  float* dinvp   = (float*)(ws + nb((size_t)N_NODES * 4));
  float* h2      = (float*)(ws + nb((size_t)N_NODES * NHID * 4));
  (void)ws_size; (void)in_sizes; (void)n_in; (void)out_size;

  hipMemsetAsync(d_ws, 0, zbytes, stream);
  count_k <<<(EE_TOT + 255) / 256, 256, 0, stream>>>(ei, counts);
  scan_k  <<<1, 1024, 0, stream>>>(counts, offsets);
  fill_k  <<<(EE_TOT + 255) / 256, 256, 0, stream>>>(ei, ew, cursor, offsets, src_s, w_s);
  gemm1_f32<<<dim3(HC / 64, (N_NODES + 63) / 64), 256, 0, stream>>>(x, Wgat, h);
  attdot  <<<N_NODES, 256, 0, stream>>>(h, atts, attd, a_src, a_dst);
  attnprep<<<N_NODES, 64, 0, stream>>>(offsets, src_s, w_s, a_src, a_dst, alpha, dinvp);
  gatagg  <<<N_NODES, 256, 0, stream>>>(offsets, src_s, alpha, h, bgat, out1);
  bnstats <<<256, 256, 0, stream>>>(out1, bnacc);
  bnfinal <<<2, 256, 0, stream>>>(bnacc, gam, bet, bnp);
  gemm2   <<<(N_NODES + 3) / 4, 256, 0, stream>>>(out1, bnp, Wgcn, h2);
  gcnagg  <<<N_NODES, 64, 0, stream>>>(offsets, src_s, w_s, dinvp, h2, bgcn, out);
}

// Round 2
// 796.464 us; speedup vs baseline: 1.5025x; 1.5025x over previous
//
#include <hip/hip_runtime.h>
#include <hip/hip_bf16.h>
#include <math.h>

#define N_NODES 30000
#define N_EDGES 480000
#define EE_TOT  510000   // edges + self loops
#define F_INK   1280
#define HC      512      // HEADS * C (4 * 128)
#define C_PH    128
#define NHID    64

typedef __attribute__((ext_vector_type(8))) short bf16x8;
typedef __attribute__((ext_vector_type(4))) float f32x4;

// ---------- wave helpers (wave64) ----------
__device__ inline float wred_max(float v){
  #pragma unroll
  for (int o = 32; o; o >>= 1) v = fmaxf(v, __shfl_xor(v, o));
  return v;
}
__device__ inline float wred_sum(float v){
  #pragma unroll
  for (int o = 32; o; o >>= 1) v += __shfl_xor(v, o);
  return v;
}

__device__ __forceinline__ unsigned short f2bf(float f){
  unsigned u = __float_as_uint(f);
  unsigned r = (u + 0x7FFFu + ((u >> 16) & 1u)) >> 16;  // RNE
  return (unsigned short)r;
}

__device__ __forceinline__ void gld16(const void* g, void* l){
  __builtin_amdgcn_global_load_lds((const __attribute__((address_space(1))) unsigned int*)g,
                                   (__attribute__((address_space(3))) unsigned int*)l, 16, 0, 0);
}

// ---------- convert x -> bf16 [30000][1280] ----------
__global__ __launch_bounds__(256) void cvtx(const float* __restrict__ x,
                                            unsigned short* __restrict__ xb){
  size_t i = ((size_t)blockIdx.x * 256 + threadIdx.x) * 4;   // 9.6M threads exactly
  float4 v = *(const float4*)&x[i];
  ushort4 o;
  o.x = f2bf(v.x); o.y = f2bf(v.y); o.z = f2bf(v.z); o.w = f2bf(v.w);
  *(ushort4*)&xb[i] = o;
}

// ---------- convert+transpose W_gat [1280][512] -> bf16 [512][1280] ----------
__global__ __launch_bounds__(256) void cvtw(const float* __restrict__ W,
                                            unsigned short* __restrict__ Wb){
  __shared__ float tile[32][33];
  int tx = threadIdx.x & 31, ty = threadIdx.x >> 5;   // 32 x 8
  int n0 = blockIdx.x * 32, k0 = blockIdx.y * 32;
  #pragma unroll
  for (int i = 0; i < 4; i++){
    int r = ty + i * 8;
    tile[r][tx] = W[(size_t)(k0 + r) * HC + n0 + tx];
  }
  __syncthreads();
  #pragma unroll
  for (int i = 0; i < 4; i++){
    int r = ty + i * 8;
    Wb[(size_t)(n0 + r) * F_INK + k0 + tx] = f2bf(tile[tx][r]);
  }
}

// ---------- GEMM1 (MFMA): h = xb @ Wb^T   [30000,1280]x[512,1280]^T -> [30000,512] ----------
// m97 structure: 128x128 tile, BK=32, 4 waves (2x2), 4x4 16x16x32 frags/wave,
// global_load_lds(16B) linear dest + inverse-swizzled global source, swizzled ds_read.
#define BM 128
#define BK 32
#define KTILES (F_INK / BK)   // 40
__global__ __launch_bounds__(256) void gemm1_mfma(const unsigned short* __restrict__ A,
                                                  const unsigned short* __restrict__ B,
                                                  float* __restrict__ C){
  __shared__ __align__(16) unsigned short Ab[2][BM * BK];  // 8 KB each
  __shared__ __align__(16) unsigned short Bb[2][BM * BK];
  const int t = threadIdx.x, lane = t & 63, wid = t >> 6;
  const int wm = wid >> 1, wn = wid & 1;
  const int bm = blockIdx.y * BM, bn = blockIdx.x * BM;
  const int r15 = lane & 15;
  const int kq  = (lane >> 4) * 16;                  // byte offset of this lane's k-group
  const int kqs = kq ^ (((r15 >> 1) & 3) << 4);      // swizzled read offset (s depends on row&15 only)
  // staging: lane covers linear tile byte L = chunk*1024 + lane*16
  const int srow  = (lane >> 2);                      // row within chunk's 16 rows
  const int skb   = ((lane & 3) * 16) ^ (((lane >> 3) & 3) << 4);  // inverse-swizzled k-byte

  f32x4 acc[4][4] = {};

  auto stage = [&](int buf, int kt){
    const int k0 = kt * BK;
    #pragma unroll
    for (int c = 0; c < 2; c++){
      int chunk = wid * 2 + c;                       // 0..7
      int row = chunk * 16 + srow;                   // 0..127
      int ar = bm + row; if (ar >= N_NODES) ar = N_NODES - 1;
      gld16(&A[(size_t)ar * F_INK + k0 + (skb >> 1)], &Ab[buf][chunk * 512]);
      gld16(&B[(size_t)(bn + row) * F_INK + k0 + (skb >> 1)], &Bb[buf][chunk * 512]);
    }
  };

  stage(0, 0);
  __syncthreads();

  for (int kt = 0; kt < KTILES; kt++){
    const int cur = kt & 1;
    if (kt + 1 < KTILES) stage(cur ^ 1, kt + 1);
    bf16x8 a[4], b[4];
    #pragma unroll
    for (int f = 0; f < 4; f++){
      int rowA = wm * 64 + f * 16 + r15;
      a[f] = *(const bf16x8*)((const char*)&Ab[cur][0] + rowA * 64 + kqs);
      int rowB = wn * 64 + f * 16 + r15;
      b[f] = *(const bf16x8*)((const char*)&Bb[cur][0] + rowB * 64 + kqs);
    }
    #pragma unroll
    for (int fm = 0; fm < 4; fm++)
      #pragma unroll
      for (int fn = 0; fn < 4; fn++)
        acc[fm][fn] = __builtin_amdgcn_mfma_f32_16x16x32_bf16(a[fm], b[fn], acc[fm][fn], 0, 0, 0);
    __syncthreads();
  }

  const int ccol0 = bn + wn * 64 + r15;
  #pragma unroll
  for (int fm = 0; fm < 4; fm++){
    #pragma unroll
    for (int j = 0; j < 4; j++){
      int row = bm + wm * 64 + fm * 16 + (lane >> 4) * 4 + j;
      if (row < N_NODES){
        #pragma unroll
        for (int fn = 0; fn < 4; fn++)
          C[(size_t)row * HC + ccol0 + fn * 16] = acc[fm][fn][j];
      }
    }
  }
}

// ---------- per-node attention dots: a_src/a_dst [N,4] ----------
__global__ __launch_bounds__(256) void attdot(const float* __restrict__ h,
    const float* __restrict__ att_s, const float* __restrict__ att_d,
    float* __restrict__ a_src, float* __restrict__ a_dst){
  int n = blockIdx.x;
  int w = threadIdx.x >> 6;      // head
  int lane = threadIdx.x & 63;
  const float* hr = h + (size_t)n * HC + w * C_PH;
  float h0 = hr[lane], h1 = hr[lane + 64];
  const float* as = att_s + w * C_PH;
  const float* ad = att_d + w * C_PH;
  float s1 = h0 * as[lane] + h1 * as[lane + 64];
  float s2 = h0 * ad[lane] + h1 * ad[lane + 64];
  s1 = wred_sum(s1); s2 = wred_sum(s2);
  if (lane == 0){ a_src[n*4 + w] = s1; a_dst[n*4 + w] = s2; }
}

// ---------- CSR build ----------
__global__ void count_k(const int* __restrict__ ei, int* __restrict__ counts){
  int e = blockIdx.x * 256 + threadIdx.x;
  if (e >= EE_TOT) return;
  int d = (e < N_EDGES) ? ei[N_EDGES + e] : (e - N_EDGES);
  atomicAdd(&counts[d], 1);
}

__global__ __launch_bounds__(1024) void scan_k(const int* __restrict__ counts,
                                               int* __restrict__ offsets){
  __shared__ int sh[1024];
  int t = threadIdx.x;
  int base = t * 30;
  int tot = 0;
  for (int i = 0; i < 30; i++){
    int idx = base + i;
    tot += (idx < N_NODES) ? counts[idx] : 0;
  }
  sh[t] = tot; __syncthreads();
  for (int o = 1; o < 1024; o <<= 1){
    int v = (t >= o) ? sh[t - o] : 0;
    __syncthreads();
    sh[t] += v;
    __syncthreads();
  }
  int run = sh[t] - tot;  // exclusive prefix
  for (int i = 0; i < 30; i++){
    int idx = base + i;
    if (idx < N_NODES){ offsets[idx] = run; run += counts[idx]; }
  }
  if (t == 1023) offsets[N_NODES] = sh[1023];
}

__global__ void fill_k(const int* __restrict__ ei, const float* __restrict__ ew,
                       int* __restrict__ cursor, const int* __restrict__ offsets,
                       int* __restrict__ src_s, float* __restrict__ w_s){
  int e = blockIdx.x * 256 + threadIdx.x;
  if (e >= EE_TOT) return;
  int s, d; float w;
  if (e < N_EDGES){ s = ei[e]; d = ei[N_EDGES + e]; w = ew[e]; }
  else            { s = d = e - N_EDGES; w = 1.0f; }
  int pos = offsets[d] + atomicAdd(&cursor[d], 1);
  src_s[pos] = s; w_s[pos] = w;
}

// ---------- segment softmax (per dst node) + GCN degree ----------
__global__ __launch_bounds__(64) void attnprep(const int* __restrict__ offsets,
    const int* __restrict__ src_s, const float* __restrict__ w_s,
    const float* __restrict__ a_src, const float* __restrict__ a_dst,
    float* __restrict__ alpha, float* __restrict__ dinv){
  int n = blockIdx.x, lane = threadIdx.x;
  int off = offsets[n], end = offsets[n + 1];
  float4 ad = *(const float4*)&a_dst[n * 4];
  float m0 = -1e30f, m1 = -1e30f, m2 = -1e30f, m3 = -1e30f;
  for (int i = off + lane; i < end; i += 64){
    int s = src_s[i];
    float4 as = *(const float4*)&a_src[s * 4];
    float l0 = as.x + ad.x; l0 = (l0 > 0.f) ? l0 : 0.2f * l0;
    float l1 = as.y + ad.y; l1 = (l1 > 0.f) ? l1 : 0.2f * l1;
    float l2 = as.z + ad.z; l2 = (l2 > 0.f) ? l2 : 0.2f * l2;
    float l3 = as.w + ad.w; l3 = (l3 > 0.f) ? l3 : 0.2f * l3;
    m0 = fmaxf(m0, l0); m1 = fmaxf(m1, l1); m2 = fmaxf(m2, l2); m3 = fmaxf(m3, l3);
  }
  m0 = wred_max(m0); m1 = wred_max(m1); m2 = wred_max(m2); m3 = wred_max(m3);
  float s0 = 0, s1 = 0, s2 = 0, s3 = 0, wsum = 0;
  for (int i = off + lane; i < end; i += 64){
    int s = src_s[i];
    float4 as = *(const float4*)&a_src[s * 4];
    float l0 = as.x + ad.x; l0 = (l0 > 0.f) ? l0 : 0.2f * l0;
    float l1 = as.y + ad.y; l1 = (l1 > 0.f) ? l1 : 0.2f * l1;
    float l2 = as.z + ad.z; l2 = (l2 > 0.f) ? l2 : 0.2f * l2;
    float l3 = as.w + ad.w; l3 = (l3 > 0.f) ? l3 : 0.2f * l3;
    float e0 = expf(l0 - m0), e1 = expf(l1 - m1), e2 = expf(l2 - m2), e3 = expf(l3 - m3);
    float4 av; av.x = e0; av.y = e1; av.z = e2; av.w = e3;
    *(float4*)&alpha[(size_t)i * 4] = av;
    s0 += e0; s1 += e1; s2 += e2; s3 += e3;
    wsum += w_s[i];
  }
  s0 = wred_sum(s0); s1 = wred_sum(s1); s2 = wred_sum(s2); s3 = wred_sum(s3);
  wsum = wred_sum(wsum);
  if (lane == 0) dinv[n] = (wsum > 0.f) ? rsqrtf(wsum) : 0.f;
  float r0 = 1.f / (s0 + 1e-16f), r1 = 1.f / (s1 + 1e-16f);
  float r2 = 1.f / (s2 + 1e-16f), r3 = 1.f / (s3 + 1e-16f);
  for (int i = off + lane; i < end; i += 64){
    float4 av = *(float4*)&alpha[(size_t)i * 4];
    av.x *= r0; av.y *= r1; av.z *= r2; av.w *= r3;
    *(float4*)&alpha[(size_t)i * 4] = av;
  }
}

// ---------- GAT message aggregation: out1[n] = sum h[src]*alpha ----------
__global__ __launch_bounds__(256) void gatagg(const int* __restrict__ offsets,
    const int* __restrict__ src_s, const float* __restrict__ alpha,
    const float* __restrict__ h, const float* __restrict__ b_gat,
    float* __restrict__ out1){
  __shared__ int    s_l[64];
  __shared__ float4 a_l[64];
  int n = blockIdx.x, t = threadIdx.x;
  int off = offsets[n], deg = offsets[n + 1] - off;
  float acc1 = 0, acc2 = 0;
  for (int done = 0; done < deg; done += 64){
    int ce = deg - done; if (ce > 64) ce = 64;
    __syncthreads();
    if (t < ce){
      s_l[t] = src_s[off + done + t];
      a_l[t] = *(const float4*)&alpha[(size_t)(off + done + t) * 4];
    }
    __syncthreads();
    for (int i = 0; i < ce; i++){
      const float* hr = h + (size_t)s_l[i] * HC;
      float4 av = a_l[i];
      float a1 = (t < 128) ? av.x : av.y;   // channel t     -> head 0/1
      float a2 = (t < 128) ? av.z : av.w;   // channel t+256 -> head 2/3
      acc1 += hr[t]       * a1;
      acc2 += hr[t + 256] * a2;
    }
  }
  out1[(size_t)n * HC + t]       = acc1 + b_gat[t];
  out1[(size_t)n * HC + t + 256] = acc2 + b_gat[t + 256];
}

// ---------- BatchNorm stats ----------
__global__ __launch_bounds__(256) void bnstats(const float* __restrict__ out1,
                                               float* __restrict__ bnacc){
  int t = threadIdx.x;
  float s1 = 0, q1 = 0, s2 = 0, q2 = 0;
  for (int n = blockIdx.x; n < N_NODES; n += gridDim.x){
    float v1 = out1[(size_t)n * HC + t];
    float v2 = out1[(size_t)n * HC + t + 256];
    s1 += v1; q1 += v1 * v1; s2 += v2; q2 += v2 * v2;
  }
  atomicAdd(&bnacc[t], s1);        atomicAdd(&bnacc[512 + t], q1);
  atomicAdd(&bnacc[t + 256], s2);  atomicAdd(&bnacc[512 + t + 256], q2);
}

__global__ void bnfinal(const float* __restrict__ bnacc, const float* __restrict__ gam,
                        const float* __restrict__ bet, float* __restrict__ bnp){
  int c = blockIdx.x * 256 + threadIdx.x;
  if (c >= 512) return;
  float mean = bnacc[c] * (1.0f / N_NODES);
  float var  = bnacc[512 + c] * (1.0f / N_NODES) - mean * mean;
  float sc = gam[c] * rsqrtf(var + 1e-5f);
  bnp[c] = sc;
  bnp[512 + c] = bet[c] - mean * sc;
}

// ---------- GEMM2 (fused BN+ReLU): h2 = relu(bn(out1)) @ W_gcn ----------
__global__ __launch_bounds__(256) void gemm2(const float* __restrict__ out1,
    const float* __restrict__ bnp, const float* __restrict__ Wg,
    float* __restrict__ h2){
  __shared__ float xr[4][512];
  __shared__ float wt[128][64];
  int t = threadIdx.x;
  int n0 = blockIdx.x * 4;
  for (int r = 0; r < 4; r++){
    int n = n0 + r;
    if (n < N_NODES){
      float v = out1[(size_t)n * HC + t] * bnp[t] + bnp[512 + t];
      xr[r][t] = v > 0.f ? v : 0.f;
      v = out1[(size_t)n * HC + t + 256] * bnp[t + 256] + bnp[512 + t + 256];
      xr[r][t + 256] = v > 0.f ? v : 0.f;
    } else { xr[r][t] = 0.f; xr[r][t + 256] = 0.f; }
  }
  int w = t >> 6, j = t & 63;
  float acc = 0.f;
  for (int k0 = 0; k0 < 512; k0 += 128){
    __syncthreads();
    for (int i = t; i < 128 * 64; i += 256)
      wt[i >> 6][i & 63] = Wg[(size_t)(k0 + (i >> 6)) * 64 + (i & 63)];
    __syncthreads();
    #pragma unroll 8
    for (int k = 0; k < 128; k++) acc += xr[w][k0 + k] * wt[k][j];
  }
  int n = n0 + w;
  if (n < N_NODES) h2[(size_t)n * NHID + j] = acc;
}

// ---------- GCN aggregation ----------
__global__ __launch_bounds__(64) void gcnagg(const int* __restrict__ offsets,
    const int* __restrict__ src_s, const float* __restrict__ w_s,
    const float* __restrict__ dinv, const float* __restrict__ h2,
    const float* __restrict__ b_gcn, float* __restrict__ out){
  int n = blockIdx.x, j = threadIdx.x;
  int off = offsets[n], end = offsets[n + 1];
  float dv = dinv[n];
  float acc = 0.f;
  for (int i = off; i < end; i++){
    int s = src_s[i];
    float nrm = dinv[s] * w_s[i] * dv;
    acc += h2[(size_t)s * NHID + j] * nrm;
  }
  out[(size_t)n * NHID + j] = acc + b_gcn[j];
}

extern "C" void kernel_launch(void* const* d_in, const int* in_sizes, int n_in,
                              void* d_out, int out_size, void* d_ws, size_t ws_size,
                              hipStream_t stream){
  const float* x    = (const float*)d_in[0];
  const int*   ei   = (const int*)d_in[1];
  const float* ew   = (const float*)d_in[2];
  const float* Wgat = (const float*)d_in[3];
  const float* atts = (const float*)d_in[4];
  const float* attd = (const float*)d_in[5];
  const float* bgat = (const float*)d_in[6];
  const float* gam  = (const float*)d_in[7];
  const float* bet  = (const float*)d_in[8];
  const float* Wgcn = (const float*)d_in[9];
  const float* bgcn = (const float*)d_in[10];
  float* out = (float*)d_out;

  char* ws = (char*)d_ws;
  size_t cur = 0;
  auto nb = [&](size_t bytes){ cur = (cur + 255) & ~(size_t)255; size_t r = cur; cur += bytes; return r; };
  int*   counts  = (int*)  (ws + nb((size_t)N_NODES * 4));
  int*   cursor  = (int*)  (ws + nb((size_t)N_NODES * 4));
  float* bnacc   = (float*)(ws + nb(1024 * 4));
  size_t zbytes  = cur;                         // everything above must start at 0
  float* h       = (float*)(ws + nb((size_t)N_NODES * HC * 4));
  float* a_src   = (float*)(ws + nb((size_t)N_NODES * 4 * 4));
  float* a_dst   = (float*)(ws + nb((size_t)N_NODES * 4 * 4));
  int*   offsets = (int*)  (ws + nb((size_t)(N_NODES + 1) * 4));
  int*   src_s   = (int*)  (ws + nb((size_t)EE_TOT * 4));
  float* w_s     = (float*)(ws + nb((size_t)EE_TOT * 4));
  // region shared by xb (GEMM1 input, dead after gemm1_mfma) and alpha/out1/h2 (live after)
  size_t reg0    = nb((size_t)EE_TOT * 16);                      // alpha
  size_t reg1    = nb((size_t)N_NODES * HC * 4);                 // out1
  size_t reg2    = nb((size_t)N_NODES * NHID * 4);               // h2
  unsigned short* xb = (unsigned short*)(ws + reg0);             // 76.8 MB spans alpha+out1+h2 (77.3 MB)
  float* alpha   = (float*)(ws + reg0);
  float* out1    = (float*)(ws + reg1);
  float* h2      = (float*)(ws + reg2);
  unsigned short* Wb = (unsigned short*)(ws + nb((size_t)HC * F_INK * 2));
  float* bnp     = (float*)(ws + nb(1024 * 4));
  float* dinvp   = (float*)(ws + nb((size_t)N_NODES * 4));
  (void)ws_size; (void)in_sizes; (void)n_in; (void)out_size;

  hipMemsetAsync(d_ws, 0, zbytes, stream);
  count_k <<<(EE_TOT + 255) / 256, 256, 0, stream>>>(ei, counts);
  scan_k  <<<1, 1024, 0, stream>>>(counts, offsets);
  fill_k  <<<(EE_TOT + 255) / 256, 256, 0, stream>>>(ei, ew, cursor, offsets, src_s, w_s);
  cvtx    <<<(N_NODES * F_INK / 4 + 255) / 256, 256, 0, stream>>>(x, xb);
  cvtw    <<<dim3(HC / 32, F_INK / 32), 256, 0, stream>>>(Wgat, Wb);
  gemm1_mfma<<<dim3(HC / BM, (N_NODES + BM - 1) / BM), 256, 0, stream>>>(xb, Wb, h);
  attdot  <<<N_NODES, 256, 0, stream>>>(h, atts, attd, a_src, a_dst);
  attnprep<<<N_NODES, 64, 0, stream>>>(offsets, src_s, w_s, a_src, a_dst, alpha, dinvp);
  gatagg  <<<N_NODES, 256, 0, stream>>>(offsets, src_s, alpha, h, bgat, out1);
  bnstats <<<256, 256, 0, stream>>>(out1, bnacc);
  bnfinal <<<2, 256, 0, stream>>>(bnacc, gam, bet, bnp);
  gemm2   <<<(N_NODES + 3) / 4, 256, 0, stream>>>(out1, bnp, Wgcn, h2);
  gcnagg  <<<N_NODES, 64, 0, stream>>>(offsets, src_s, w_s, dinvp, h2, bgcn, out);
}

// Round 3
// 629.008 us; speedup vs baseline: 1.9025x; 1.2662x over previous
//
#include <hip/hip_runtime.h>
#include <hip/hip_bf16.h>
#include <math.h>

#define N_NODES 30000
#define N_EDGES 480000
#define EE_TOT  510000   // edges + self loops
#define F_INK   1280
#define HC      512      // HEADS * C (4 * 128)
#define C_PH    128
#define NHID    64

typedef __attribute__((ext_vector_type(8))) short bf16x8;
typedef __attribute__((ext_vector_type(4))) float f32x4;

// ---------- wave helpers (wave64) ----------
__device__ inline float wred_max(float v){
  #pragma unroll
  for (int o = 32; o; o >>= 1) v = fmaxf(v, __shfl_xor(v, o));
  return v;
}
__device__ inline float wred_sum(float v){
  #pragma unroll
  for (int o = 32; o; o >>= 1) v += __shfl_xor(v, o);
  return v;
}

__device__ __forceinline__ unsigned short f2bf(float f){
  unsigned u = __float_as_uint(f);
  unsigned r = (u + 0x7FFFu + ((u >> 16) & 1u)) >> 16;  // RNE
  return (unsigned short)r;
}
__device__ __forceinline__ float b2f(unsigned short s){
  return __uint_as_float((unsigned)s << 16);
}

__device__ __forceinline__ void gld16(const void* g, void* l){
  __builtin_amdgcn_global_load_lds((const __attribute__((address_space(1))) unsigned int*)g,
                                   (__attribute__((address_space(3))) unsigned int*)l, 16, 0, 0);
}

// ---------- convert x -> bf16 [30000][1280] ----------
__global__ __launch_bounds__(256) void cvtx(const float* __restrict__ x,
                                            unsigned short* __restrict__ xb){
  size_t i = ((size_t)blockIdx.x * 256 + threadIdx.x) * 4;   // 9.6M elements exactly
  float4 v = *(const float4*)&x[i];
  ushort4 o;
  o.x = f2bf(v.x); o.y = f2bf(v.y); o.z = f2bf(v.z); o.w = f2bf(v.w);
  *(ushort4*)&xb[i] = o;
}

// ---------- convert+transpose W_gat [1280][512] -> bf16 [512][1280] ----------
__global__ __launch_bounds__(256) void cvtw(const float* __restrict__ W,
                                            unsigned short* __restrict__ Wb){
  __shared__ float tile[32][33];
  int tx = threadIdx.x & 31, ty = threadIdx.x >> 5;   // 32 x 8
  int n0 = blockIdx.x * 32, k0 = blockIdx.y * 32;
  #pragma unroll
  for (int i = 0; i < 4; i++){
    int r = ty + i * 8;
    tile[r][tx] = W[(size_t)(k0 + r) * HC + n0 + tx];
  }
  __syncthreads();
  #pragma unroll
  for (int i = 0; i < 4; i++){
    int r = ty + i * 8;
    Wb[(size_t)(n0 + r) * F_INK + k0 + tx] = f2bf(tile[tx][r]);
  }
}

// ---------- convert+transpose W_gcn [512][64] -> bf16 [64][512] ----------
__global__ __launch_bounds__(256) void cvtw2(const float* __restrict__ W,
                                             unsigned short* __restrict__ Wb){
  __shared__ float tile[32][33];
  int tx = threadIdx.x & 31, ty = threadIdx.x >> 5;
  int n0 = blockIdx.x * 32, k0 = blockIdx.y * 32;
  #pragma unroll
  for (int i = 0; i < 4; i++){
    int r = ty + i * 8;
    tile[r][tx] = W[(size_t)(k0 + r) * NHID + n0 + tx];
  }
  __syncthreads();
  #pragma unroll
  for (int i = 0; i < 4; i++){
    int r = ty + i * 8;
    Wb[(size_t)(n0 + r) * HC + k0 + tx] = f2bf(tile[tx][r]);
  }
}

// ---------- GEMM1 (MFMA): hb = bf16( xb @ Wb^T )  [30000,1280]x[512,1280]^T ----------
#define BM 128
#define BK 32
#define KTILES (F_INK / BK)   // 40
__global__ __launch_bounds__(256) void gemm1_mfma(const unsigned short* __restrict__ A,
                                                  const unsigned short* __restrict__ B,
                                                  unsigned short* __restrict__ C){
  __shared__ __align__(16) unsigned short Ab[2][BM * BK];  // 8 KB each
  __shared__ __align__(16) unsigned short Bb[2][BM * BK];
  const int t = threadIdx.x, lane = t & 63, wid = t >> 6;
  const int wm = wid >> 1, wn = wid & 1;
  const int bm = blockIdx.y * BM, bn = blockIdx.x * BM;
  const int r15 = lane & 15;
  const int kq  = (lane >> 4) * 16;                  // byte offset of this lane's k-group
  const int kqs = kq ^ (((r15 >> 1) & 3) << 4);      // swizzled read offset
  const int srow  = (lane >> 2);                     // row within chunk's 16 rows
  const int skb   = ((lane & 3) * 16) ^ (((lane >> 3) & 3) << 4);  // inverse-swizzled k-byte

  f32x4 acc[4][4] = {};

  auto stage = [&](int buf, int kt){
    const int k0 = kt * BK;
    #pragma unroll
    for (int c = 0; c < 2; c++){
      int chunk = wid * 2 + c;                       // 0..7
      int row = chunk * 16 + srow;                   // 0..127
      int ar = bm + row; if (ar >= N_NODES) ar = N_NODES - 1;
      gld16(&A[(size_t)ar * F_INK + k0 + (skb >> 1)], &Ab[buf][chunk * 512]);
      gld16(&B[(size_t)(bn + row) * F_INK + k0 + (skb >> 1)], &Bb[buf][chunk * 512]);
    }
  };

  stage(0, 0);
  __syncthreads();

  for (int kt = 0; kt < KTILES; kt++){
    const int cur = kt & 1;
    if (kt + 1 < KTILES) stage(cur ^ 1, kt + 1);
    bf16x8 a[4], b[4];
    #pragma unroll
    for (int f = 0; f < 4; f++){
      int rowA = wm * 64 + f * 16 + r15;
      a[f] = *(const bf16x8*)((const char*)&Ab[cur][0] + rowA * 64 + kqs);
      int rowB = wn * 64 + f * 16 + r15;
      b[f] = *(const bf16x8*)((const char*)&Bb[cur][0] + rowB * 64 + kqs);
    }
    #pragma unroll
    for (int fm = 0; fm < 4; fm++)
      #pragma unroll
      for (int fn = 0; fn < 4; fn++)
        acc[fm][fn] = __builtin_amdgcn_mfma_f32_16x16x32_bf16(a[fm], b[fn], acc[fm][fn], 0, 0, 0);
    __syncthreads();
  }

  const int ccol0 = bn + wn * 64 + r15;
  #pragma unroll
  for (int fm = 0; fm < 4; fm++){
    #pragma unroll
    for (int j = 0; j < 4; j++){
      int row = bm + wm * 64 + fm * 16 + (lane >> 4) * 4 + j;
      if (row < N_NODES){
        #pragma unroll
        for (int fn = 0; fn < 4; fn++)
          C[(size_t)row * HC + ccol0 + fn * 16] = f2bf(acc[fm][fn][j]);
      }
    }
  }
}

// ---------- per-node attention dots: a_src/a_dst [N,4] (bf16 h) ----------
__global__ __launch_bounds__(256) void attdot(const unsigned short* __restrict__ hb,
    const float* __restrict__ att_s, const float* __restrict__ att_d,
    float* __restrict__ a_src, float* __restrict__ a_dst){
  int n = blockIdx.x;
  int w = threadIdx.x >> 6;      // head
  int lane = threadIdx.x & 63;
  const unsigned short* hr = hb + (size_t)n * HC + w * C_PH;
  ushort2 hv = *(const ushort2*)(hr + 2 * lane);
  float h0 = b2f(hv.x), h1 = b2f(hv.y);
  const float* as = att_s + w * C_PH;
  const float* ad = att_d + w * C_PH;
  float s1 = h0 * as[2*lane] + h1 * as[2*lane + 1];
  float s2 = h0 * ad[2*lane] + h1 * ad[2*lane + 1];
  s1 = wred_sum(s1); s2 = wred_sum(s2);
  if (lane == 0){ a_src[n*4 + w] = s1; a_dst[n*4 + w] = s2; }
}

// ---------- CSR build ----------
__global__ void count_k(const int* __restrict__ ei, int* __restrict__ counts){
  int e = blockIdx.x * 256 + threadIdx.x;
  if (e >= EE_TOT) return;
  int d = (e < N_EDGES) ? ei[N_EDGES + e] : (e - N_EDGES);
  atomicAdd(&counts[d], 1);
}

__global__ __launch_bounds__(1024) void scan_k(const int* __restrict__ counts,
                                               int* __restrict__ offsets){
  __shared__ int sh[1024];
  int t = threadIdx.x;
  int base = t * 30;
  int tot = 0;
  for (int i = 0; i < 30; i++){
    int idx = base + i;
    tot += (idx < N_NODES) ? counts[idx] : 0;
  }
  sh[t] = tot; __syncthreads();
  for (int o = 1; o < 1024; o <<= 1){
    int v = (t >= o) ? sh[t - o] : 0;
    __syncthreads();
    sh[t] += v;
    __syncthreads();
  }
  int run = sh[t] - tot;  // exclusive prefix
  for (int i = 0; i < 30; i++){
    int idx = base + i;
    if (idx < N_NODES){ offsets[idx] = run; run += counts[idx]; }
  }
  if (t == 1023) offsets[N_NODES] = sh[1023];
}

__global__ void fill_k(const int* __restrict__ ei, const float* __restrict__ ew,
                       int* __restrict__ cursor, const int* __restrict__ offsets,
                       int* __restrict__ src_s, float* __restrict__ w_s){
  int e = blockIdx.x * 256 + threadIdx.x;
  if (e >= EE_TOT) return;
  int s, d; float w;
  if (e < N_EDGES){ s = ei[e]; d = ei[N_EDGES + e]; w = ew[e]; }
  else            { s = d = e - N_EDGES; w = 1.0f; }
  int pos = offsets[d] + atomicAdd(&cursor[d], 1);
  src_s[pos] = s; w_s[pos] = w;
}

// ---------- segment softmax (per dst node) + GCN degree ----------
__global__ __launch_bounds__(64) void attnprep(const int* __restrict__ offsets,
    const int* __restrict__ src_s, const float* __restrict__ w_s,
    const float* __restrict__ a_src, const float* __restrict__ a_dst,
    float* __restrict__ alpha, float* __restrict__ dinv){
  int n = blockIdx.x, lane = threadIdx.x;
  int off = offsets[n], end = offsets[n + 1];
  float4 ad = *(const float4*)&a_dst[n * 4];
  float m0 = -1e30f, m1 = -1e30f, m2 = -1e30f, m3 = -1e30f;
  for (int i = off + lane; i < end; i += 64){
    int s = src_s[i];
    float4 as = *(const float4*)&a_src[s * 4];
    float l0 = as.x + ad.x; l0 = (l0 > 0.f) ? l0 : 0.2f * l0;
    float l1 = as.y + ad.y; l1 = (l1 > 0.f) ? l1 : 0.2f * l1;
    float l2 = as.z + ad.z; l2 = (l2 > 0.f) ? l2 : 0.2f * l2;
    float l3 = as.w + ad.w; l3 = (l3 > 0.f) ? l3 : 0.2f * l3;
    m0 = fmaxf(m0, l0); m1 = fmaxf(m1, l1); m2 = fmaxf(m2, l2); m3 = fmaxf(m3, l3);
  }
  m0 = wred_max(m0); m1 = wred_max(m1); m2 = wred_max(m2); m3 = wred_max(m3);
  float s0 = 0, s1 = 0, s2 = 0, s3 = 0, wsum = 0;
  for (int i = off + lane; i < end; i += 64){
    int s = src_s[i];
    float4 as = *(const float4*)&a_src[s * 4];
    float l0 = as.x + ad.x; l0 = (l0 > 0.f) ? l0 : 0.2f * l0;
    float l1 = as.y + ad.y; l1 = (l1 > 0.f) ? l1 : 0.2f * l1;
    float l2 = as.z + ad.z; l2 = (l2 > 0.f) ? l2 : 0.2f * l2;
    float l3 = as.w + ad.w; l3 = (l3 > 0.f) ? l3 : 0.2f * l3;
    float e0 = expf(l0 - m0), e1 = expf(l1 - m1), e2 = expf(l2 - m2), e3 = expf(l3 - m3);
    float4 av; av.x = e0; av.y = e1; av.z = e2; av.w = e3;
    *(float4*)&alpha[(size_t)i * 4] = av;
    s0 += e0; s1 += e1; s2 += e2; s3 += e3;
    wsum += w_s[i];
  }
  s0 = wred_sum(s0); s1 = wred_sum(s1); s2 = wred_sum(s2); s3 = wred_sum(s3);
  wsum = wred_sum(wsum);
  if (lane == 0) dinv[n] = (wsum > 0.f) ? rsqrtf(wsum) : 0.f;
  float r0 = 1.f / (s0 + 1e-16f), r1 = 1.f / (s1 + 1e-16f);
  float r2 = 1.f / (s2 + 1e-16f), r3 = 1.f / (s3 + 1e-16f);
  for (int i = off + lane; i < end; i += 64){
    float4 av = *(float4*)&alpha[(size_t)i * 4];
    av.x *= r0; av.y *= r1; av.z *= r2; av.w *= r3;
    *(float4*)&alpha[(size_t)i * 4] = av;
  }
}

// ---------- GAT message aggregation (bf16 h): out1[n] = sum hb[src]*alpha ----------
__global__ __launch_bounds__(256) void gatagg(const int* __restrict__ offsets,
    const int* __restrict__ src_s, const float* __restrict__ alpha,
    const unsigned short* __restrict__ hb, const float* __restrict__ b_gat,
    float* __restrict__ out1){
  __shared__ int   s_l[64];
  __shared__ float a_s[64][4];
  int n = blockIdx.x, t = threadIdx.x, wid = t >> 6;  // wid == head for channels 2t,2t+1
  int off = offsets[n], deg = offsets[n + 1] - off;
  float acc0 = 0, acc1 = 0;
  for (int done = 0; done < deg; done += 64){
    int ce = deg - done; if (ce > 64) ce = 64;
    __syncthreads();
    if (t < 64 && t < ce){
      int idx = off + done + t;
      s_l[t] = src_s[idx];
      float4 av = *(const float4*)&alpha[(size_t)idx * 4];
      a_s[t][0] = av.x; a_s[t][1] = av.y; a_s[t][2] = av.z; a_s[t][3] = av.w;
    }
    __syncthreads();
    for (int i = 0; i < ce; i++){
      const ushort2* hp = (const ushort2*)(hb + (size_t)s_l[i] * HC);
      ushort2 hv = hp[t];
      float a = a_s[i][wid];           // LDS broadcast (wave-uniform)
      acc0 += b2f(hv.x) * a;
      acc1 += b2f(hv.y) * a;
    }
  }
  float2 o; o.x = acc0 + b_gat[2*t]; o.y = acc1 + b_gat[2*t + 1];
  *(float2*)&out1[(size_t)n * HC + 2*t] = o;
}

// ---------- BatchNorm stats ----------
__global__ __launch_bounds__(256) void bnstats(const float* __restrict__ out1,
                                               float* __restrict__ bnacc){
  int t = threadIdx.x;
  float s1 = 0, q1 = 0, s2 = 0, q2 = 0;
  for (int n = blockIdx.x; n < N_NODES; n += gridDim.x){
    float v1 = out1[(size_t)n * HC + t];
    float v2 = out1[(size_t)n * HC + t + 256];
    s1 += v1; q1 += v1 * v1; s2 += v2; q2 += v2 * v2;
  }
  atomicAdd(&bnacc[t], s1);        atomicAdd(&bnacc[512 + t], q1);
  atomicAdd(&bnacc[t + 256], s2);  atomicAdd(&bnacc[512 + t + 256], q2);
}

__global__ void bnfinal(const float* __restrict__ bnacc, const float* __restrict__ gam,
                        const float* __restrict__ bet, float* __restrict__ bnp){
  int c = blockIdx.x * 256 + threadIdx.x;
  if (c >= 512) return;
  float mean = bnacc[c] * (1.0f / N_NODES);
  float var  = bnacc[512 + c] * (1.0f / N_NODES) - mean * mean;
  float sc = gam[c] * rsqrtf(var + 1e-5f);
  bnp[c] = sc;
  bnp[512 + c] = bet[c] - mean * sc;
}

// ---------- BN+ReLU+cvt: xrb = bf16(relu(out1*sc+sh)) ----------
__global__ __launch_bounds__(256) void bnprep(const float* __restrict__ out1,
    const float* __restrict__ bnp, unsigned short* __restrict__ xrb){
  size_t i = ((size_t)blockIdx.x * 256 + threadIdx.x) * 4;  // over N*512 = 15.36M
  int c = (int)(i & (HC - 1));
  float4 v  = *(const float4*)&out1[i];
  float4 sc = *(const float4*)&bnp[c];
  float4 sh = *(const float4*)&bnp[512 + c];
  float r; ushort4 o;
  r = v.x * sc.x + sh.x; o.x = f2bf(r > 0.f ? r : 0.f);
  r = v.y * sc.y + sh.y; o.y = f2bf(r > 0.f ? r : 0.f);
  r = v.z * sc.z + sh.z; o.z = f2bf(r > 0.f ? r : 0.f);
  r = v.w * sc.w + sh.w; o.w = f2bf(r > 0.f ? r : 0.f);
  *(ushort4*)&xrb[i] = o;
}

// ---------- GEMM2 (MFMA): h2 = xrb @ Wtb^T  [30000,512]x[64,512]^T ----------
#define BM2 128
#define BK2 32
__global__ __launch_bounds__(256) void gemm2_mfma(const unsigned short* __restrict__ A,
                                                  const unsigned short* __restrict__ B,
                                                  float* __restrict__ C){
  __shared__ __align__(16) unsigned short Ab[2][BM2 * BK2];  // 8 KB each
  __shared__ __align__(16) unsigned short Bb[2][NHID * BK2]; // 4 KB each
  const int t = threadIdx.x, lane = t & 63, wid = t >> 6;
  const int bm = blockIdx.x * BM2;
  const int r15 = lane & 15;
  const int kq  = (lane >> 4) * 16;
  const int kqs = kq ^ (((r15 >> 1) & 3) << 4);
  const int srow = lane >> 2;
  const int skb  = ((lane & 3) * 16) ^ (((lane >> 3) & 3) << 4);

  f32x4 acc[2][4] = {};

  auto stage = [&](int buf, int kt){
    const int k0 = kt * BK2;
    #pragma unroll
    for (int c = 0; c < 2; c++){
      int chunk = wid * 2 + c;                  // 0..7
      int row = chunk * 16 + srow;              // 0..127
      int ar = bm + row; if (ar >= N_NODES) ar = N_NODES - 1;
      gld16(&A[(size_t)ar * HC + k0 + (skb >> 1)], &Ab[buf][chunk * 512]);
    }
    int rowB = wid * 16 + srow;                 // 0..63
    gld16(&B[(size_t)rowB * HC + k0 + (skb >> 1)], &Bb[buf][wid * 512]);
  };

  stage(0, 0);
  __syncthreads();

  #pragma unroll 2
  for (int kt = 0; kt < HC / BK2; kt++){        // 16 steps
    const int cur = kt & 1;
    if (kt + 1 < HC / BK2) stage(cur ^ 1, kt + 1);
    bf16x8 a[2], b[4];
    #pragma unroll
    for (int f = 0; f < 2; f++){
      int rowA = wid * 32 + f * 16 + r15;
      a[f] = *(const bf16x8*)((const char*)&Ab[cur][0] + rowA * 64 + kqs);
    }
    #pragma unroll
    for (int f = 0; f < 4; f++){
      int rowB = f * 16 + r15;
      b[f] = *(const bf16x8*)((const char*)&Bb[cur][0] + rowB * 64 + kqs);
    }
    #pragma unroll
    for (int fm = 0; fm < 2; fm++)
      #pragma unroll
      for (int fn = 0; fn < 4; fn++)
        acc[fm][fn] = __builtin_amdgcn_mfma_f32_16x16x32_bf16(a[fm], b[fn], acc[fm][fn], 0, 0, 0);
    __syncthreads();
  }

  #pragma unroll
  for (int fm = 0; fm < 2; fm++){
    #pragma unroll
    for (int j = 0; j < 4; j++){
      int row = bm + wid * 32 + fm * 16 + (lane >> 4) * 4 + j;
      if (row < N_NODES){
        #pragma unroll
        for (int fn = 0; fn < 4; fn++)
          C[(size_t)row * NHID + fn * 16 + r15] = acc[fm][fn][j];
      }
    }
  }
}

// ---------- GCN aggregation ----------
__global__ __launch_bounds__(64) void gcnagg(const int* __restrict__ offsets,
    const int* __restrict__ src_s, const float* __restrict__ w_s,
    const float* __restrict__ dinv, const float* __restrict__ h2,
    const float* __restrict__ b_gcn, float* __restrict__ out){
  int n = blockIdx.x, j = threadIdx.x;
  int off = offsets[n], end = offsets[n + 1];
  float dv = dinv[n];
  float acc = 0.f;
  for (int i = off; i < end; i++){
    int s = src_s[i];
    float nrm = dinv[s] * w_s[i] * dv;
    acc += h2[(size_t)s * NHID + j] * nrm;
  }
  out[(size_t)n * NHID + j] = acc + b_gcn[j];
}

extern "C" void kernel_launch(void* const* d_in, const int* in_sizes, int n_in,
                              void* d_out, int out_size, void* d_ws, size_t ws_size,
                              hipStream_t stream){
  const float* x    = (const float*)d_in[0];
  const int*   ei   = (const int*)d_in[1];
  const float* ew   = (const float*)d_in[2];
  const float* Wgat = (const float*)d_in[3];
  const float* atts = (const float*)d_in[4];
  const float* attd = (const float*)d_in[5];
  const float* bgat = (const float*)d_in[6];
  const float* gam  = (const float*)d_in[7];
  const float* bet  = (const float*)d_in[8];
  const float* Wgcn = (const float*)d_in[9];
  const float* bgcn = (const float*)d_in[10];
  float* out = (float*)d_out;

  char* ws = (char*)d_ws;
  size_t cur = 0;
  auto nb = [&](size_t bytes){ cur = (cur + 255) & ~(size_t)255; size_t r = cur; cur += bytes; return r; };
  int*   counts  = (int*)  (ws + nb((size_t)N_NODES * 4));
  int*   cursor  = (int*)  (ws + nb((size_t)N_NODES * 4));
  float* bnacc   = (float*)(ws + nb(1024 * 4));
  size_t zbytes  = cur;                         // everything above must start at 0
  unsigned short* hb = (unsigned short*)(ws + nb((size_t)N_NODES * HC * 2));  // bf16 h
  float* a_src   = (float*)(ws + nb((size_t)N_NODES * 4 * 4));
  float* a_dst   = (float*)(ws + nb((size_t)N_NODES * 4 * 4));
  int*   offsets = (int*)  (ws + nb((size_t)(N_NODES + 1) * 4));
  int*   src_s   = (int*)  (ws + nb((size_t)EE_TOT * 4));
  float* w_s     = (float*)(ws + nb((size_t)EE_TOT * 4));
  // region shared by xb (GEMM1 input, dead after gemm1_mfma) and alpha/out1/h2 (live after)
  size_t reg0    = nb((size_t)EE_TOT * 16);                      // alpha   (8.2 MB)
  size_t reg1    = nb((size_t)N_NODES * HC * 4);                 // out1    (61.4 MB)
  size_t reg2    = nb((size_t)N_NODES * NHID * 4);               // h2      (7.7 MB)
  unsigned short* xb = (unsigned short*)(ws + reg0);             // 76.8 MB spans alpha+out1+h2
  float* alpha   = (float*)(ws + reg0);
  float* out1    = (float*)(ws + reg1);
  float* h2      = (float*)(ws + reg2);
  unsigned short* Wb  = (unsigned short*)(ws + nb((size_t)HC * F_INK * 2));   // 1.3 MB
  unsigned short* Wtb = (unsigned short*)(ws + nb((size_t)NHID * HC * 2));    // 64 KB
  unsigned short* xrb = (unsigned short*)(ws + nb((size_t)N_NODES * HC * 2)); // 30.7 MB
  float* bnp     = (float*)(ws + nb(1024 * 4));
  float* dinvp   = (float*)(ws + nb((size_t)N_NODES * 4));
  (void)ws_size; (void)in_sizes; (void)n_in; (void)out_size;

  hipMemsetAsync(d_ws, 0, zbytes, stream);
  count_k <<<(EE_TOT + 255) / 256, 256, 0, stream>>>(ei, counts);
  scan_k  <<<1, 1024, 0, stream>>>(counts, offsets);
  fill_k  <<<(EE_TOT + 255) / 256, 256, 0, stream>>>(ei, ew, cursor, offsets, src_s, w_s);
  cvtx    <<<(N_NODES * F_INK / 4 + 255) / 256, 256, 0, stream>>>(x, xb);
  cvtw    <<<dim3(HC / 32, F_INK / 32), 256, 0, stream>>>(Wgat, Wb);
  cvtw2   <<<dim3(NHID / 32, HC / 32), 256, 0, stream>>>(Wgcn, Wtb);
  gemm1_mfma<<<dim3(HC / BM, (N_NODES + BM - 1) / BM), 256, 0, stream>>>(xb, Wb, hb);
  attdot  <<<N_NODES, 256, 0, stream>>>(hb, atts, attd, a_src, a_dst);
  attnprep<<<N_NODES, 64, 0, stream>>>(offsets, src_s, w_s, a_src, a_dst, alpha, dinvp);
  gatagg  <<<N_NODES, 256, 0, stream>>>(offsets, src_s, alpha, hb, bgat, out1);
  bnstats <<<256, 256, 0, stream>>>(out1, bnacc);
  bnfinal <<<2, 256, 0, stream>>>(bnacc, gam, bet, bnp);
  bnprep  <<<N_NODES * HC / 4 / 256, 256, 0, stream>>>(out1, bnp, xrb);
  gemm2_mfma<<<(N_NODES + BM2 - 1) / BM2, 256, 0, stream>>>(xrb, Wtb, h2);
  gcnagg  <<<N_NODES, 64, 0, stream>>>(offsets, src_s, w_s, dinvp, h2, bgcn, out);
}

// Round 5
// 624.313 us; speedup vs baseline: 1.9168x; 1.0075x over previous
//
#include <hip/hip_runtime.h>
#include <hip/hip_bf16.h>
#include <math.h>

#define N_NODES 30000
#define N_EDGES 480000
#define EE_TOT  510000   // edges + self loops
#define F_INK   1280
#define HC      512      // HEADS * C (4 * 128)
#define C_PH    128
#define NHID    64

typedef __attribute__((ext_vector_type(8))) short bf16x8;
typedef __attribute__((ext_vector_type(4))) float f32x4;

// ---------- wave helpers (wave64) ----------
__device__ inline float wred_max(float v){
  #pragma unroll
  for (int o = 32; o; o >>= 1) v = fmaxf(v, __shfl_xor(v, o));
  return v;
}
__device__ inline float wred_sum(float v){
  #pragma unroll
  for (int o = 32; o; o >>= 1) v += __shfl_xor(v, o);
  return v;
}

__device__ __forceinline__ unsigned short f2bf(float f){
  unsigned u = __float_as_uint(f);
  unsigned r = (u + 0x7FFFu + ((u >> 16) & 1u)) >> 16;  // RNE
  return (unsigned short)r;
}
__device__ __forceinline__ float b2f(unsigned short s){
  return __uint_as_float((unsigned)s << 16);
}

__device__ __forceinline__ void gld16(const void* g, void* l){
  __builtin_amdgcn_global_load_lds((const __attribute__((address_space(1))) unsigned int*)g,
                                   (__attribute__((address_space(3))) unsigned int*)l, 16, 0, 0);
}

// ---------- convert x -> bf16 [30000][1280] ----------
__global__ __launch_bounds__(256) void cvtx(const float* __restrict__ x,
                                            unsigned short* __restrict__ xb){
  size_t i = ((size_t)blockIdx.x * 256 + threadIdx.x) * 4;   // 9.6M elements exactly
  float4 v = *(const float4*)&x[i];
  ushort4 o;
  o.x = f2bf(v.x); o.y = f2bf(v.y); o.z = f2bf(v.z); o.w = f2bf(v.w);
  *(ushort4*)&xb[i] = o;
}

// ---------- convert+transpose W_gat [1280][512] -> bf16 [512][1280] ----------
__global__ __launch_bounds__(256) void cvtw(const float* __restrict__ W,
                                            unsigned short* __restrict__ Wb){
  __shared__ float tile[32][33];
  int tx = threadIdx.x & 31, ty = threadIdx.x >> 5;   // 32 x 8
  int n0 = blockIdx.x * 32, k0 = blockIdx.y * 32;
  #pragma unroll
  for (int i = 0; i < 4; i++){
    int r = ty + i * 8;
    tile[r][tx] = W[(size_t)(k0 + r) * HC + n0 + tx];
  }
  __syncthreads();
  #pragma unroll
  for (int i = 0; i < 4; i++){
    int r = ty + i * 8;
    Wb[(size_t)(n0 + r) * F_INK + k0 + tx] = f2bf(tile[tx][r]);
  }
}

// ---------- convert+transpose W_gcn [512][64] -> bf16 [64][512] ----------
__global__ __launch_bounds__(256) void cvtw2(const float* __restrict__ W,
                                             unsigned short* __restrict__ Wb){
  __shared__ float tile[32][33];
  int tx = threadIdx.x & 31, ty = threadIdx.x >> 5;
  int n0 = blockIdx.x * 32, k0 = blockIdx.y * 32;
  #pragma unroll
  for (int i = 0; i < 4; i++){
    int r = ty + i * 8;
    tile[r][tx] = W[(size_t)(k0 + r) * NHID + n0 + tx];
  }
  __syncthreads();
  #pragma unroll
  for (int i = 0; i < 4; i++){
    int r = ty + i * 8;
    Wb[(size_t)(n0 + r) * HC + k0 + tx] = f2bf(tile[tx][r]);
  }
}

// ---------- GEMM1 (MFMA): hb = bf16( xb @ Wb^T )  [30000,1280]x[512,1280]^T ----------
// BM=64 x BN=256 block, 4 waves arranged 1x4, per-wave 64x64 acc[4][4] (m97 fragment
// code unchanged). Halves A-refetch vs BN=128; B (1.31 MB) is L2-resident.
#define BM1 64
#define BN1 256
#define BK 32
#define KTILES (F_INK / BK)   // 40
__global__ __launch_bounds__(256) void gemm1_mfma(const unsigned short* __restrict__ A,
                                                  const unsigned short* __restrict__ B,
                                                  unsigned short* __restrict__ C){
  __shared__ __align__(16) unsigned short Ab[2][BM1 * BK];  // 4 KB each
  __shared__ __align__(16) unsigned short Bb[2][BN1 * BK];  // 16 KB each
  const int t = threadIdx.x, lane = t & 63, wid = t >> 6;   // wn == wid (1x4)
  const int bm = blockIdx.y * BM1, bn = blockIdx.x * BN1;
  const int r15 = lane & 15;
  const int kq  = (lane >> 4) * 16;                  // byte offset of this lane's k-group
  const int kqs = kq ^ (((r15 >> 1) & 3) << 4);      // swizzled read offset
  const int srow  = (lane >> 2);                     // row within chunk's 16 rows
  const int skb   = ((lane & 3) * 16) ^ (((lane >> 3) & 3) << 4);  // inverse-swizzled k-byte

  f32x4 acc[4][4] = {};

  auto stage = [&](int buf, int kt){
    const int k0 = kt * BK;
    {
      int row = wid * 16 + srow;                     // A: 4 chunks of 16 rows
      int ar = bm + row; if (ar >= N_NODES) ar = N_NODES - 1;
      gld16(&A[(size_t)ar * F_INK + k0 + (skb >> 1)], &Ab[buf][wid * 512]);
    }
    #pragma unroll
    for (int c = 0; c < 4; c++){
      int ch = wid * 4 + c;                          // B: 16 chunks of 16 rows
      gld16(&B[(size_t)(bn + ch * 16 + srow) * F_INK + k0 + (skb >> 1)], &Bb[buf][ch * 512]);
    }
  };

  stage(0, 0);
  __syncthreads();

  for (int kt = 0; kt < KTILES; kt++){
    const int cur = kt & 1;
    if (kt + 1 < KTILES) stage(cur ^ 1, kt + 1);
    bf16x8 a[4], b[4];
    #pragma unroll
    for (int f = 0; f < 4; f++){
      int rowA = f * 16 + r15;
      a[f] = *(const bf16x8*)((const char*)&Ab[cur][0] + rowA * 64 + kqs);
      int rowB = wid * 64 + f * 16 + r15;
      b[f] = *(const bf16x8*)((const char*)&Bb[cur][0] + rowB * 64 + kqs);
    }
    #pragma unroll
    for (int fm = 0; fm < 4; fm++)
      #pragma unroll
      for (int fn = 0; fn < 4; fn++)
        acc[fm][fn] = __builtin_amdgcn_mfma_f32_16x16x32_bf16(a[fm], b[fn], acc[fm][fn], 0, 0, 0);
    __syncthreads();
  }

  const int ccol0 = bn + wid * 64 + r15;
  #pragma unroll
  for (int fm = 0; fm < 4; fm++){
    #pragma unroll
    for (int j = 0; j < 4; j++){
      int row = bm + fm * 16 + (lane >> 4) * 4 + j;
      if (row < N_NODES){
        #pragma unroll
        for (int fn = 0; fn < 4; fn++)
          C[(size_t)row * HC + ccol0 + fn * 16] = f2bf(acc[fm][fn][j]);
      }
    }
  }
}

// ---------- per-node attention dots: a_src/a_dst [N,4] (bf16 h) ----------
__global__ __launch_bounds__(256) void attdot(const unsigned short* __restrict__ hb,
    const float* __restrict__ att_s, const float* __restrict__ att_d,
    float* __restrict__ a_src, float* __restrict__ a_dst){
  int n = blockIdx.x;
  int w = threadIdx.x >> 6;      // head
  int lane = threadIdx.x & 63;
  const unsigned short* hr = hb + (size_t)n * HC + w * C_PH;
  ushort2 hv = *(const ushort2*)(hr + 2 * lane);
  float h0 = b2f(hv.x), h1 = b2f(hv.y);
  const float* as = att_s + w * C_PH;
  const float* ad = att_d + w * C_PH;
  float s1 = h0 * as[2*lane] + h1 * as[2*lane + 1];
  float s2 = h0 * ad[2*lane] + h1 * ad[2*lane + 1];
  s1 = wred_sum(s1); s2 = wred_sum(s2);
  if (lane == 0){ a_src[n*4 + w] = s1; a_dst[n*4 + w] = s2; }
}

// ---------- CSR build ----------
__global__ void count_k(const int* __restrict__ ei, int* __restrict__ counts){
  int e = blockIdx.x * 256 + threadIdx.x;
  if (e >= EE_TOT) return;
  int d = (e < N_EDGES) ? ei[N_EDGES + e] : (e - N_EDGES);
  atomicAdd(&counts[d], 1);
}

__global__ __launch_bounds__(1024) void scan_k(const int* __restrict__ counts,
                                               int* __restrict__ offsets){
  __shared__ int sh[1024];
  int t = threadIdx.x;
  int base = t * 30;
  int tot = 0;
  for (int i = 0; i < 30; i++){
    int idx = base + i;
    tot += (idx < N_NODES) ? counts[idx] : 0;
  }
  sh[t] = tot; __syncthreads();
  for (int o = 1; o < 1024; o <<= 1){
    int v = (t >= o) ? sh[t - o] : 0;
    __syncthreads();
    sh[t] += v;
    __syncthreads();
  }
  int run = sh[t] - tot;  // exclusive prefix
  for (int i = 0; i < 30; i++){
    int idx = base + i;
    if (idx < N_NODES){ offsets[idx] = run; run += counts[idx]; }
  }
  if (t == 1023) offsets[N_NODES] = sh[1023];
}

__global__ void fill_k(const int* __restrict__ ei, const float* __restrict__ ew,
                       int* __restrict__ cursor, const int* __restrict__ offsets,
                       int* __restrict__ src_s, float* __restrict__ w_s){
  int e = blockIdx.x * 256 + threadIdx.x;
  if (e >= EE_TOT) return;
  int s, d; float w;
  if (e < N_EDGES){ s = ei[e]; d = ei[N_EDGES + e]; w = ew[e]; }
  else            { s = d = e - N_EDGES; w = 1.0f; }
  int pos = offsets[d] + atomicAdd(&cursor[d], 1);
  src_s[pos] = s; w_s[pos] = w;
}

// ---------- segment softmax (per dst node) + GCN degree ----------
__global__ __launch_bounds__(64) void attnprep(const int* __restrict__ offsets,
    const int* __restrict__ src_s, const float* __restrict__ w_s,
    const float* __restrict__ a_src, const float* __restrict__ a_dst,
    float* __restrict__ alpha, float* __restrict__ dinv){
  int n = blockIdx.x, lane = threadIdx.x;
  int off = offsets[n], end = offsets[n + 1];
  float4 ad = *(const float4*)&a_dst[n * 4];
  float m0 = -1e30f, m1 = -1e30f, m2 = -1e30f, m3 = -1e30f;
  for (int i = off + lane; i < end; i += 64){
    int s = src_s[i];
    float4 as = *(const float4*)&a_src[s * 4];
    float l0 = as.x + ad.x; l0 = (l0 > 0.f) ? l0 : 0.2f * l0;
    float l1 = as.y + ad.y; l1 = (l1 > 0.f) ? l1 : 0.2f * l1;
    float l2 = as.z + ad.z; l2 = (l2 > 0.f) ? l2 : 0.2f * l2;
    float l3 = as.w + ad.w; l3 = (l3 > 0.f) ? l3 : 0.2f * l3;
    m0 = fmaxf(m0, l0); m1 = fmaxf(m1, l1); m2 = fmaxf(m2, l2); m3 = fmaxf(m3, l3);
  }
  m0 = wred_max(m0); m1 = wred_max(m1); m2 = wred_max(m2); m3 = wred_max(m3);
  float s0 = 0, s1 = 0, s2 = 0, s3 = 0, wsum = 0;
  for (int i = off + lane; i < end; i += 64){
    int s = src_s[i];
    float4 as = *(const float4*)&a_src[s * 4];
    float l0 = as.x + ad.x; l0 = (l0 > 0.f) ? l0 : 0.2f * l0;
    float l1 = as.y + ad.y; l1 = (l1 > 0.f) ? l1 : 0.2f * l1;
    float l2 = as.z + ad.z; l2 = (l2 > 0.f) ? l2 : 0.2f * l2;
    float l3 = as.w + ad.w; l3 = (l3 > 0.f) ? l3 : 0.2f * l3;
    float e0 = expf(l0 - m0), e1 = expf(l1 - m1), e2 = expf(l2 - m2), e3 = expf(l3 - m3);
    float4 av; av.x = e0; av.y = e1; av.z = e2; av.w = e3;
    *(float4*)&alpha[(size_t)i * 4] = av;
    s0 += e0; s1 += e1; s2 += e2; s3 += e3;
    wsum += w_s[i];
  }
  s0 = wred_sum(s0); s1 = wred_sum(s1); s2 = wred_sum(s2); s3 = wred_sum(s3);
  wsum = wred_sum(wsum);
  if (lane == 0) dinv[n] = (wsum > 0.f) ? rsqrtf(wsum) : 0.f;
  float r0 = 1.f / (s0 + 1e-16f), r1 = 1.f / (s1 + 1e-16f);
  float r2 = 1.f / (s2 + 1e-16f), r3 = 1.f / (s3 + 1e-16f);
  for (int i = off + lane; i < end; i += 64){
    float4 av = *(float4*)&alpha[(size_t)i * 4];
    av.x *= r0; av.y *= r1; av.z *= r2; av.w *= r3;
    *(float4*)&alpha[(size_t)i * 4] = av;
  }
}

// ---------- GAT message aggregation (bf16 h): out1b = bf16( sum hb[src]*alpha + b ) ----------
__global__ __launch_bounds__(256) void gatagg(const int* __restrict__ offsets,
    const int* __restrict__ src_s, const float* __restrict__ alpha,
    const unsigned short* __restrict__ hb, const float* __restrict__ b_gat,
    unsigned short* __restrict__ out1b){
  __shared__ int   s_l[64];
  __shared__ float a_s[64][4];
  int n = blockIdx.x, t = threadIdx.x, wid = t >> 6;  // wid == head for channels 2t,2t+1
  int off = offsets[n], deg = offsets[n + 1] - off;
  float acc0 = 0, acc1 = 0;
  for (int done = 0; done < deg; done += 64){
    int ce = deg - done; if (ce > 64) ce = 64;
    __syncthreads();
    if (t < 64 && t < ce){
      int idx = off + done + t;
      s_l[t] = src_s[idx];
      float4 av = *(const float4*)&alpha[(size_t)idx * 4];
      a_s[t][0] = av.x; a_s[t][1] = av.y; a_s[t][2] = av.z; a_s[t][3] = av.w;
    }
    __syncthreads();
    for (int i = 0; i < ce; i++){
      const ushort2* hp = (const ushort2*)(hb + (size_t)s_l[i] * HC);
      ushort2 hv = hp[t];
      float a = a_s[i][wid];           // LDS broadcast (wave-uniform)
      acc0 += b2f(hv.x) * a;
      acc1 += b2f(hv.y) * a;
    }
  }
  ushort2 o;
  o.x = f2bf(acc0 + b_gat[2*t]);
  o.y = f2bf(acc1 + b_gat[2*t + 1]);
  *(ushort2*)&out1b[(size_t)n * HC + 2*t] = o;
}

// ---------- BatchNorm stats (bf16 out1) ----------
__global__ __launch_bounds__(256) void bnstats(const unsigned short* __restrict__ out1b,
                                               float* __restrict__ bnacc){
  int t = threadIdx.x;                 // channels 2t, 2t+1
  float s1 = 0, q1 = 0, s2 = 0, q2 = 0;
  for (int n = blockIdx.x; n < N_NODES; n += gridDim.x){
    ushort2 v = *(const ushort2*)&out1b[(size_t)n * HC + 2*t];
    float v1 = b2f(v.x), v2 = b2f(v.y);
    s1 += v1; q1 += v1 * v1; s2 += v2; q2 += v2 * v2;
  }
  atomicAdd(&bnacc[2*t], s1);      atomicAdd(&bnacc[512 + 2*t], q1);
  atomicAdd(&bnacc[2*t + 1], s2);  atomicAdd(&bnacc[512 + 2*t + 1], q2);
}

__global__ void bnfinal(const float* __restrict__ bnacc, const float* __restrict__ gam,
                        const float* __restrict__ bet, float* __restrict__ bnp){
  int c = blockIdx.x * 256 + threadIdx.x;
  if (c >= 512) return;
  float mean = bnacc[c] * (1.0f / N_NODES);
  float var  = bnacc[512 + c] * (1.0f / N_NODES) - mean * mean;
  float sc = gam[c] * rsqrtf(var + 1e-5f);
  bnp[c] = sc;
  bnp[512 + c] = bet[c] - mean * sc;
}

// ---------- BN+ReLU+cvt: xrb = bf16(relu(out1b*sc+sh)) ----------
__global__ __launch_bounds__(256) void bnprep(const unsigned short* __restrict__ out1b,
    const float* __restrict__ bnp, unsigned short* __restrict__ xrb){
  size_t i = ((size_t)blockIdx.x * 256 + threadIdx.x) * 4;  // over N*512 = 15.36M
  int c = (int)(i & (HC - 1));
  ushort4 v4 = *(const ushort4*)&out1b[i];
  float4 sc = *(const float4*)&bnp[c];
  float4 sh = *(const float4*)&bnp[512 + c];
  float r; ushort4 o;
  r = b2f(v4.x) * sc.x + sh.x; o.x = f2bf(r > 0.f ? r : 0.f);
  r = b2f(v4.y) * sc.y + sh.y; o.y = f2bf(r > 0.f ? r : 0.f);
  r = b2f(v4.z) * sc.z + sh.z; o.z = f2bf(r > 0.f ? r : 0.f);
  r = b2f(v4.w) * sc.w + sh.w; o.w = f2bf(r > 0.f ? r : 0.f);
  *(ushort4*)&xrb[i] = o;
}

// ---------- GEMM2 (MFMA): h2 = xrb @ Wtb^T  [30000,512]x[64,512]^T ----------
#define BM2 128
#define BK2 32
__global__ __launch_bounds__(256) void gemm2_mfma(const unsigned short* __restrict__ A,
                                                  const unsigned short* __restrict__ B,
                                                  float* __restrict__ C){
  __shared__ __align__(16) unsigned short Ab[2][BM2 * BK2];  // 8 KB each
  __shared__ __align__(16) unsigned short Bb[2][NHID * BK2]; // 4 KB each
  const int t = threadIdx.x, lane = t & 63, wid = t >> 6;
  const int bm = blockIdx.x * BM2;
  const int r15 = lane & 15;
  const int kq  = (lane >> 4) * 16;
  const int kqs = kq ^ (((r15 >> 1) & 3) << 4);
  const int srow = lane >> 2;
  const int skb  = ((lane & 3) * 16) ^ (((lane >> 3) & 3) << 4);

  f32x4 acc[2][4] = {};

  auto stage = [&](int buf, int kt){
    const int k0 = kt * BK2;
    #pragma unroll
    for (int c = 0; c < 2; c++){
      int chunk = wid * 2 + c;                  // 0..7
      int row = chunk * 16 + srow;              // 0..127
      int ar = bm + row; if (ar >= N_NODES) ar = N_NODES - 1;
      gld16(&A[(size_t)ar * HC + k0 + (skb >> 1)], &Ab[buf][chunk * 512]);
    }
    int rowB = wid * 16 + srow;                 // 0..63
    gld16(&B[(size_t)rowB * HC + k0 + (skb >> 1)], &Bb[buf][wid * 512]);
  };

  stage(0, 0);
  __syncthreads();

  #pragma unroll 2
  for (int kt = 0; kt < HC / BK2; kt++){        // 16 steps
    const int cur = kt & 1;
    if (kt + 1 < HC / BK2) stage(cur ^ 1, kt + 1);
    bf16x8 a[2], b[4];
    #pragma unroll
    for (int f = 0; f < 2; f++){
      int rowA = wid * 32 + f * 16 + r15;
      a[f] = *(const bf16x8*)((const char*)&Ab[cur][0] + rowA * 64 + kqs);
    }
    #pragma unroll
    for (int f = 0; f < 4; f++){
      int rowB = f * 16 + r15;
      b[f] = *(const bf16x8*)((const char*)&Bb[cur][0] + rowB * 64 + kqs);
    }
    #pragma unroll
    for (int fm = 0; fm < 2; fm++)
      #pragma unroll
      for (int fn = 0; fn < 4; fn++)
        acc[fm][fn] = __builtin_amdgcn_mfma_f32_16x16x32_bf16(a[fm], b[fn], acc[fm][fn], 0, 0, 0);
    __syncthreads();
  }

  #pragma unroll
  for (int fm = 0; fm < 2; fm++){
    #pragma unroll
    for (int j = 0; j < 4; j++){
      int row = bm + wid * 32 + fm * 16 + (lane >> 4) * 4 + j;
      if (row < N_NODES){
        #pragma unroll
        for (int fn = 0; fn < 4; fn++)
          C[(size_t)row * NHID + fn * 16 + r15] = acc[fm][fn][j];
      }
    }
  }
}

// ---------- GCN aggregation ----------
__global__ __launch_bounds__(64) void gcnagg(const int* __restrict__ offsets,
    const int* __restrict__ src_s, const float* __restrict__ w_s,
    const float* __restrict__ dinv, const float* __restrict__ h2,
    const float* __restrict__ b_gcn, float* __restrict__ out){
  int n = blockIdx.x, j = threadIdx.x;
  int off = offsets[n], end = offsets[n + 1];
  float dv = dinv[n];
  float acc = 0.f;
  for (int i = off; i < end; i++){
    int s = src_s[i];
    float nrm = dinv[s] * w_s[i] * dv;
    acc += h2[(size_t)s * NHID + j] * nrm;
  }
  out[(size_t)n * NHID + j] = acc + b_gcn[j];
}

extern "C" void kernel_launch(void* const* d_in, const int* in_sizes, int n_in,
                              void* d_out, int out_size, void* d_ws, size_t ws_size,
                              hipStream_t stream){
  const float* x    = (const float*)d_in[0];
  const int*   ei   = (const int*)d_in[1];
  const float* ew   = (const float*)d_in[2];
  const float* Wgat = (const float*)d_in[3];
  const float* atts = (const float*)d_in[4];
  const float* attd = (const float*)d_in[5];
  const float* bgat = (const float*)d_in[6];
  const float* gam  = (const float*)d_in[7];
  const float* bet  = (const float*)d_in[8];
  const float* Wgcn = (const float*)d_in[9];
  const float* bgcn = (const float*)d_in[10];
  float* out = (float*)d_out;

  char* ws = (char*)d_ws;
  size_t cur = 0;
  auto nb = [&](size_t bytes){ cur = (cur + 255) & ~(size_t)255; size_t r = cur; cur += bytes; return r; };
  int*   counts  = (int*)  (ws + nb((size_t)N_NODES * 4));
  int*   cursor  = (int*)  (ws + nb((size_t)N_NODES * 4));
  float* bnacc   = (float*)(ws + nb(1024 * 4));
  size_t zbytes  = cur;                         // everything above must start at 0
  unsigned short* hb = (unsigned short*)(ws + nb((size_t)N_NODES * HC * 2));  // bf16 h
  float* a_src   = (float*)(ws + nb((size_t)N_NODES * 4 * 4));
  float* a_dst   = (float*)(ws + nb((size_t)N_NODES * 4 * 4));
  int*   offsets = (int*)  (ws + nb((size_t)(N_NODES + 1) * 4));
  int*   src_s   = (int*)  (ws + nb((size_t)EE_TOT * 4));
  float* w_s     = (float*)(ws + nb((size_t)EE_TOT * 4));
  // region shared by xb (GEMM1 input, dead after gemm1_mfma) and alpha/out1b/h2 (live after)
  size_t reg0    = nb((size_t)EE_TOT * 16);                      // alpha   (8.2 MB)
  size_t reg1    = nb((size_t)N_NODES * HC * 4);                 // out1b   (reserved fp32-size)
  size_t reg2    = nb((size_t)N_NODES * NHID * 4);               // h2      (7.7 MB)
  unsigned short* xb = (unsigned short*)(ws + reg0);             // 76.8 MB spans alpha+out1b+h2
  float* alpha   = (float*)(ws + reg0);
  unsigned short* out1b = (unsigned short*)(ws + reg1);
  float* h2      = (float*)(ws + reg2);
  unsigned short* Wb  = (unsigned short*)(ws + nb((size_t)HC * F_INK * 2));   // 1.3 MB
  unsigned short* Wtb = (unsigned short*)(ws + nb((size_t)NHID * HC * 2));    // 64 KB
  unsigned short* xrb = (unsigned short*)(ws + nb((size_t)N_NODES * HC * 2)); // 30.7 MB
  float* bnp     = (float*)(ws + nb(1024 * 4));
  float* dinvp   = (float*)(ws + nb((size_t)N_NODES * 4));
  (void)ws_size; (void)in_sizes; (void)n_in; (void)out_size;

  hipMemsetAsync(d_ws, 0, zbytes, stream);
  count_k <<<(EE_TOT + 255) / 256, 256, 0, stream>>>(ei, counts);
  scan_k  <<<1, 1024, 0, stream>>>(counts, offsets);
  fill_k  <<<(EE_TOT + 255) / 256, 256, 0, stream>>>(ei, ew, cursor, offsets, src_s, w_s);
  cvtx    <<<(N_NODES * F_INK / 4 + 255) / 256, 256, 0, stream>>>(x, xb);
  cvtw    <<<dim3(HC / 32, F_INK / 32), 256, 0, stream>>>(Wgat, Wb);
  cvtw2   <<<dim3(NHID / 32, HC / 32), 256, 0, stream>>>(Wgcn, Wtb);
  gemm1_mfma<<<dim3(HC / BN1, (N_NODES + BM1 - 1) / BM1), 256, 0, stream>>>(xb, Wb, hb);
  attdot  <<<N_NODES, 256, 0, stream>>>(hb, atts, attd, a_src, a_dst);
  attnprep<<<N_NODES, 64, 0, stream>>>(offsets, src_s, w_s, a_src, a_dst, alpha, dinvp);
  gatagg  <<<N_NODES, 256, 0, stream>>>(offsets, src_s, alpha, hb, bgat, out1b);
  bnstats <<<256, 256, 0, stream>>>(out1b, bnacc);
  bnfinal <<<2, 256, 0, stream>>>(bnacc, gam, bet, bnp);
  bnprep  <<<N_NODES * HC / 4 / 256, 256, 0, stream>>>(out1b, bnp, xrb);
  gemm2_mfma<<<(N_NODES + BM2 - 1) / BM2, 256, 0, stream>>>(xrb, Wtb, h2);
  gcnagg  <<<N_NODES, 64, 0, stream>>>(offsets, src_s, w_s, dinvp, h2, bgcn, out);
}